// Round 9
// baseline (206.788 us; speedup 1.0000x reference)
//
#include <hip/hip_runtime.h>

#define N_NODES 50000
#define N_EDGES 800000
#define DIM 128
#define CHUNK 4096      // edges per chunk; 196*4096 >= 800000
#define GRID 196        // chunks == buckets == blocks for build passes
#define SEG_CAP 6144    // LDS csr segment cap (mean 4096, sigma 64)
#define GEMM_BLOCKS 391 // ceil(50000/128) -- 128 rows per block
#define GA 391          // ALL layer-1 gemm blocks co-gridded with sort (587 total, ~3/CU resident)

typedef __attribute__((ext_vector_type(8))) short bf16x8;   // 8 bf16 = 4 VGPRs
typedef __attribute__((ext_vector_type(4))) float f32x4;    // MFMA acc

// ---------------- bf16 pack/unpack (RNE) ----------------

__device__ inline unsigned rne_bf16(float f) {
    unsigned u = __float_as_uint(f);
    return (u + 0x7FFFu + ((u >> 16) & 1u)) >> 16;
}
__device__ inline unsigned pk_bf16(float a, float b) {
    return rne_bf16(a) | (rne_bf16(b) << 16);
}
__device__ inline float bf_lo(unsigned u) { return __uint_as_float(u << 16); }
__device__ inline float bf_hi(unsigned u) { return __uint_as_float(u & 0xFFFF0000u); }

// ---------------- W -> MFMA fragment pre-pass (bf16 hi/lo split) -----------

__device__ void fragw_build(const float* __restrict__ W, uint4* __restrict__ fh,
                            uint4* __restrict__ fl, int slot) {
    const int lane = slot & 63, tile = slot >> 6;     // tile 0..31
    const int c = tile >> 2, q = tile & 3;
    const int k0 = q * 32 + ((lane >> 4) << 3);
    const int col = c * 16 + (lane & 15);
    unsigned h[8], l[8];
#pragma unroll
    for (int j = 0; j < 8; ++j) {
        float w = W[(size_t)(k0 + j) * DIM + col];
        unsigned hb = rne_bf16(w);
        h[j] = hb;
        l[j] = rne_bf16(w - __uint_as_float(hb << 16));
    }
    uint4 uh, ul;
    uh.x = h[0] | (h[1] << 16); uh.y = h[2] | (h[3] << 16);
    uh.z = h[4] | (h[5] << 16); uh.w = h[6] | (h[7] << 16);
    ul.x = l[0] | (l[1] << 16); ul.y = l[2] | (l[3] << 16);
    ul.z = l[4] | (l[5] << 16); ul.w = l[6] | (l[7] << 16);
    fh[slot] = uh;
    fl[slot] = ul;
}

// ---------------- Pass A + fragW: co-gridded ----------------

__global__ __launch_bounds__(256) void chunk_hist_fragw(const int* __restrict__ dst,
                                                        int* __restrict__ chist,
                                                        const float* __restrict__ W1,
                                                        const float* __restrict__ W2,
                                                        uint4* f1h, uint4* f1l,
                                                        uint4* f2h, uint4* f2l) {
    const int bid = blockIdx.x;
    if (bid < GRID) {
        __shared__ int hist[256];
        const int t = threadIdx.x;
        const int eb = bid * CHUNK;
        const int cnt = min(CHUNK, N_EDGES - eb);
        hist[t] = 0;
        __syncthreads();
        for (int i = t; i < cnt; i += 256)
            atomicAdd(&hist[dst[eb + i] >> 8], 1);
        __syncthreads();
        chist[bid * 256 + t] = hist[t];
    } else {
        const int b2 = bid - GRID;                    // 0..15
        const int slot = (b2 & 7) * 256 + threadIdx.x; // 0..2047
        if (b2 < 8) fragw_build(W1, f1h, f1l, slot);
        else        fragw_build(W2, f2h, f2l, slot);
    }
}

// ---------------- MFMA GEMM body (layer 1): O = X[fp32] @ W, bf16 out ------
// B fragments read DIRECTLY from L2-resident tables (zero per-block reuse,
// staging removed). Epilogue bounces through 32KB LDS in two 64-row halves.

__device__ void gemm_body(const float* __restrict__ X,
                          const uint4* __restrict__ fWh,
                          const uint4* __restrict__ fWl,
                          uint2* __restrict__ O, int gb, char* smem) {
    const int t = threadIdx.x;
    const int w = t >> 6, lane = t & 63;
    const int lrow = lane & 15, lgrp = lane >> 4;
    const int rbase = gb * 128;

    bf16x8 Ah[2][4], Al[2][4];
#pragma unroll
    for (int m = 0; m < 2; ++m) {
        const int r = rbase + w * 32 + m * 16 + lrow;
        const bool ok = (r < N_NODES);
        const float4* xp = (const float4*)(X + (size_t)r * DIM + lgrp * 8);
#pragma unroll
        for (int q = 0; q < 4; ++q) {
            float4 a0 = ok ? xp[q * 8]     : make_float4(0.f, 0.f, 0.f, 0.f);
            float4 a1 = ok ? xp[q * 8 + 1] : make_float4(0.f, 0.f, 0.f, 0.f);
            float f[8] = {a0.x, a0.y, a0.z, a0.w, a1.x, a1.y, a1.z, a1.w};
            bf16x8 hi, lo;
#pragma unroll
            for (int j = 0; j < 8; ++j) {
                unsigned hb = rne_bf16(f[j]);
                hi[j] = (short)hb;
                lo[j] = (short)rne_bf16(f[j] - __uint_as_float(hb << 16));
            }
            Ah[m][q] = hi;
            Al[m][q] = lo;
        }
    }

    f32x4 acc[2][8];
#pragma unroll
    for (int m = 0; m < 2; ++m)
#pragma unroll
        for (int c = 0; c < 8; ++c)
            acc[m][c] = (f32x4){0.f, 0.f, 0.f, 0.f};

    const bf16x8* Bh = (const bf16x8*)fWh;
    const bf16x8* Bl = (const bf16x8*)fWl;
#pragma unroll
    for (int c = 0; c < 8; ++c) {
#pragma unroll
        for (int q = 0; q < 4; ++q) {
            bf16x8 bh = Bh[(c * 4 + q) * 64 + lane];
            bf16x8 bl = Bl[(c * 4 + q) * 64 + lane];
#pragma unroll
            for (int m = 0; m < 2; ++m) {
                acc[m][c] = __builtin_amdgcn_mfma_f32_16x16x32_bf16(Ah[m][q], bh, acc[m][c], 0, 0, 0);
                acc[m][c] = __builtin_amdgcn_mfma_f32_16x16x32_bf16(Al[m][q], bh, acc[m][c], 0, 0, 0);
                acc[m][c] = __builtin_amdgcn_mfma_f32_16x16x32_bf16(Ah[m][q], bl, acc[m][c], 0, 0, 0);
            }
        }
    }

    // epilogue: two halves (m=0 rows w*32+0..15, m=1 rows w*32+16..31)
    float* Lf = (float*)smem;              // [64][128] fp32
#pragma unroll
    for (int m = 0; m < 2; ++m) {
        __syncthreads();
#pragma unroll
        for (int c = 0; c < 8; ++c)
#pragma unroll
            for (int rg = 0; rg < 4; ++rg)
                Lf[(w * 16 + lgrp * 4 + rg) * 128 + c * 16 + lrow] = acc[m][c][rg];
        __syncthreads();
        const float4* Lf4 = (const float4*)smem;
        for (int idx = t; idx < 2048; idx += 256) {
            const int rl = idx >> 5, s = idx & 31;
            const int gr = rbase + (rl >> 4) * 32 + m * 16 + (rl & 15);
            if (gr < N_NODES) {
                float4 v = Lf4[idx];
                uint2 o;
                o.x = pk_bf16(v.x, v.y);
                o.y = pk_bf16(v.z, v.w);
                O[(size_t)gr * 32 + s] = o;
            }
        }
    }
}

// ---------------- Pass B body: counting sort; offsets from chist -----------

__device__ void sort_scatter_body(const int* __restrict__ src,
                                  const int* __restrict__ dst,
                                  const int* __restrict__ chist,
                                  unsigned* __restrict__ sorted,
                                  int* __restrict__ bbase_g,
                                  int bid, char* smem) {
    int* hist  = (int*)smem;
    int* sc    = hist + 256;
    int* lbase = sc + 256;
    int* lcur  = lbase + 256;
    int* gbase = lcur + 256;
    unsigned* sl = (unsigned*)(smem + 5 * 1024);   // CHUNK entries

    const int t = threadIdx.x;
    const int eb = bid * CHUNK;
    const int cnt = min(CHUNK, N_EDGES - eb);

    int sum = 0, myoff = 0;
    for (int c = 0; c < GRID; ++c) {
        int v = chist[c * 256 + t];
        if (c == bid) myoff = sum;
        sum += v;
    }
    hist[t] = chist[bid * 256 + t];
    sc[t] = sum;
    __syncthreads();
    for (int off = 1; off < 256; off <<= 1) {
        int u = (t >= off) ? sc[t - off] : 0;
        __syncthreads();
        sc[t] += u;
        __syncthreads();
    }
    gbase[t] = (sc[t] - sum) + myoff;
    if (bid == 0) bbase_g[t] = sc[t] - sum;   // exclusive scan of bucket totals
    __syncthreads();

    sc[t] = hist[t];
    __syncthreads();
    for (int off = 1; off < 256; off <<= 1) {
        int u = (t >= off) ? sc[t - off] : 0;
        __syncthreads();
        sc[t] += u;
        __syncthreads();
    }
    int ex = sc[t] - hist[t];
    lbase[t] = ex;
    lcur[t] = ex;
    __syncthreads();

    for (int i = t; i < cnt; i += 256) {
        int s = src[eb + i], d = dst[eb + i];
        int b = d >> 8;
        int p = atomicAdd(&lcur[b], 1);
        sl[p] = ((unsigned)b << 24) | ((unsigned)(d & 255) << 16) | (unsigned)s;
    }
    __syncthreads();
    for (int i = t; i < cnt; i += 256) {
        unsigned rec = sl[i];
        int b = rec >> 24;
        sorted[gbase[b] + (i - lbase[b])] = rec;
    }
}

// ---------------- Pass C: per-bucket CSR finalize (standalone, 5/CU) -------

__global__ __launch_bounds__(256) void csr_build(const unsigned* __restrict__ sorted,
                                                 const int* __restrict__ bbase,
                                                 int* __restrict__ rowptr,
                                                 float* __restrict__ dinv,
                                                 int* __restrict__ csr) {
    __shared__ __align__(16) char smem[3 * 1024 + SEG_CAP * 4];   // 27.6 KB
    int* hist = (int*)smem;
    int* sc   = hist + 256;
    int* lcur = sc + 256;
    int* seg  = (int*)(smem + 3 * 1024);

    const int k = blockIdx.x;
    const int t = threadIdx.x;
    const int base = bbase[k];
    const int cntk = ((k == 255) ? N_EDGES : bbase[k + 1]) - base;
    if (k == 0 && t == 0) rowptr[N_NODES] = N_EDGES;

    hist[t] = 0;
    __syncthreads();
    for (int i = t; i < cntk; i += 256)
        atomicAdd(&hist[(sorted[base + i] >> 16) & 255], 1);
    __syncthreads();

    const int node = (k << 8) + t;
    const int dv = hist[t];
    if (node < N_NODES) dinv[node] = rsqrtf((float)dv + 1.0f);   // +1 self-loop

    sc[t] = dv;
    __syncthreads();
    for (int off = 1; off < 256; off <<= 1) {
        int u = (t >= off) ? sc[t - off] : 0;
        __syncthreads();
        sc[t] += u;
        __syncthreads();
    }
    int ex = sc[t] - dv;
    if (node < N_NODES) rowptr[node] = base + ex;
    lcur[t] = ex;
    __syncthreads();

    if (cntk <= SEG_CAP) {
        for (int i = t; i < cntk; i += 256) {
            unsigned rec = sorted[base + i];
            int p = atomicAdd(&lcur[(rec >> 16) & 255], 1);
            seg[p] = (int)(rec & 0xFFFFu);
        }
        __syncthreads();
        for (int i = t; i < cntk; i += 256)
            csr[base + i] = seg[i];
    } else {
        for (int i = t; i < cntk; i += 256) {
            unsigned rec = sorted[base + i];
            int p = atomicAdd(&lcur[(rec >> 16) & 255], 1);
            csr[base + p] = (int)(rec & 0xFFFFu);
        }
    }
}

// ---------------- Fused dispatch: sort blocks first, ALL gemm1 backfills ---

__global__ __launch_bounds__(256) void sort_gemm(const int* __restrict__ src,
                                                 const int* __restrict__ dst,
                                                 const int* __restrict__ chist,
                                                 unsigned* __restrict__ sorted,
                                                 int* __restrict__ bbase_g,
                                                 const float* __restrict__ X,
                                                 const uint4* __restrict__ fWh,
                                                 const uint4* __restrict__ fWl,
                                                 uint2* __restrict__ O) {
    __shared__ __align__(16) char smem[32768];
    if (blockIdx.x < GRID)
        sort_scatter_body(src, dst, chist, sorted, bbase_g, blockIdx.x, smem);
    else
        gemm_body(X, fWh, fWl, O, blockIdx.x - GRID, smem);
}

// ---------------- quarter-wave aggregation (uint4 = 16B/lane gathers) ------

#define ACC8_D(v, d) do { \
        a0 = fmaf((d), bf_lo((v).x), a0); a1 = fmaf((d), bf_hi((v).x), a1); \
        a2 = fmaf((d), bf_lo((v).y), a2); a3 = fmaf((d), bf_hi((v).y), a3); \
        a4 = fmaf((d), bf_lo((v).z), a4); a5 = fmaf((d), bf_hi((v).z), a5); \
        a6 = fmaf((d), bf_lo((v).w), a6); a7 = fmaf((d), bf_hi((v).w), a7); } while (0)

#define ACC8_P(v) do { \
        a0 += bf_lo((v).x); a1 += bf_hi((v).x); \
        a2 += bf_lo((v).y); a3 += bf_hi((v).y); \
        a4 += bf_lo((v).z); a5 += bf_hi((v).z); \
        a6 += bf_lo((v).w); a7 += bf_hi((v).w); } while (0)

// ---------------- layer-1 aggregate: per-edge dinv fmaf; writes h1' hi/lo --
// h1' = dinv[n] * relu(agg*dn + b1)  -> pre-scaled for layer 2 (linearity).

__global__ __launch_bounds__(256) void aggregate_h1(const uint2* __restrict__ H2,
                                                    const int* __restrict__ rowptr,
                                                    const int* __restrict__ csr,
                                                    const float* __restrict__ dinv,
                                                    const float4* __restrict__ b4,
                                                    uint4* __restrict__ h1h4,
                                                    uint4* __restrict__ h1l4) {
    const int node = blockIdx.x * 4 + (threadIdx.x >> 6);
    if (node >= N_NODES) return;
    const int lane = threadIdx.x & 63;
    const int q = lane >> 4, l16 = lane & 15;
    const uint4* H4 = (const uint4*)H2;

    const float dn = dinv[node];
    float a0 = 0.f, a1 = 0.f, a2 = 0.f, a3 = 0.f,
          a4 = 0.f, a5 = 0.f, a6 = 0.f, a7 = 0.f;
    if (q == 0) {                          // self-loop term: weight dinv[node]
        uint4 v = H4[(size_t)node * 16 + l16];
        ACC8_D(v, dn);
    }

    int j = rowptr[node];
    const int end = rowptr[node + 1];
    for (; j + 8 <= end; j += 8) {         // 2 gathers in flight per quarter
        int s0 = csr[j + q], s1 = csr[j + 4 + q];
        uint4 v0 = H4[(size_t)s0 * 16 + l16]; float d0 = dinv[s0];
        uint4 v1 = H4[(size_t)s1 * 16 + l16]; float d1 = dinv[s1];
        ACC8_D(v0, d0); ACC8_D(v1, d1);
    }
    if (j + 4 <= end) {
        int s = csr[j + q];
        uint4 v = H4[(size_t)s * 16 + l16]; float d = dinv[s];
        ACC8_D(v, d);
        j += 4;
    }
    if (q < end - j) {
        int s = csr[j + q];
        uint4 v = H4[(size_t)s * 16 + l16]; float d = dinv[s];
        ACC8_D(v, d);
    }

    a0 += __shfl_xor(a0, 16, 64); a1 += __shfl_xor(a1, 16, 64);
    a2 += __shfl_xor(a2, 16, 64); a3 += __shfl_xor(a3, 16, 64);
    a4 += __shfl_xor(a4, 16, 64); a5 += __shfl_xor(a5, 16, 64);
    a6 += __shfl_xor(a6, 16, 64); a7 += __shfl_xor(a7, 16, 64);
    a0 += __shfl_xor(a0, 32, 64); a1 += __shfl_xor(a1, 32, 64);
    a2 += __shfl_xor(a2, 32, 64); a3 += __shfl_xor(a3, 32, 64);
    a4 += __shfl_xor(a4, 32, 64); a5 += __shfl_xor(a5, 32, 64);
    a6 += __shfl_xor(a6, 32, 64); a7 += __shfl_xor(a7, 32, 64);

    if (lane < 16) {
        float4 bbA = b4[l16 * 2], bbB = b4[l16 * 2 + 1];
        float o0 = fmaxf(a0 * dn + bbA.x, 0.f), o1 = fmaxf(a1 * dn + bbA.y, 0.f);
        float o2 = fmaxf(a2 * dn + bbA.z, 0.f), o3 = fmaxf(a3 * dn + bbA.w, 0.f);
        float o4 = fmaxf(a4 * dn + bbB.x, 0.f), o5 = fmaxf(a5 * dn + bbB.y, 0.f);
        float o6 = fmaxf(a6 * dn + bbB.z, 0.f), o7 = fmaxf(a7 * dn + bbB.w, 0.f);
        o0 *= dn; o1 *= dn; o2 *= dn; o3 *= dn;
        o4 *= dn; o5 *= dn; o6 *= dn; o7 *= dn;
        unsigned h0 = rne_bf16(o0), h1 = rne_bf16(o1), h2 = rne_bf16(o2), h3 = rne_bf16(o3);
        unsigned h4 = rne_bf16(o4), h5 = rne_bf16(o5), h6 = rne_bf16(o6), h7 = rne_bf16(o7);
        uint4 hv;
        hv.x = h0 | (h1 << 16); hv.y = h2 | (h3 << 16);
        hv.z = h4 | (h5 << 16); hv.w = h6 | (h7 << 16);
        uint4 lv;
        lv.x = rne_bf16(o0 - __uint_as_float(h0 << 16)) |
               (rne_bf16(o1 - __uint_as_float(h1 << 16)) << 16);
        lv.y = rne_bf16(o2 - __uint_as_float(h2 << 16)) |
               (rne_bf16(o3 - __uint_as_float(h3 << 16)) << 16);
        lv.z = rne_bf16(o4 - __uint_as_float(h4 << 16)) |
               (rne_bf16(o5 - __uint_as_float(h5 << 16)) << 16);
        lv.w = rne_bf16(o6 - __uint_as_float(h6 << 16)) |
               (rne_bf16(o7 - __uint_as_float(h7 << 16)) << 16);
        h1h4[(size_t)node * 16 + l16] = hv;
        h1l4[(size_t)node * 16 + l16] = lv;
    }
}

// ---------------- final aggregate: hp2 pre-scaled -> plain adds ------------

__global__ __launch_bounds__(256) void aggregate_out(const uint2* __restrict__ H2,
                                                     const int* __restrict__ rowptr,
                                                     const int* __restrict__ csr,
                                                     const float* __restrict__ dinv,
                                                     const float4* __restrict__ b4,
                                                     float4* __restrict__ out) {
    const int node = blockIdx.x * 4 + (threadIdx.x >> 6);
    if (node >= N_NODES) return;
    const int lane = threadIdx.x & 63;
    const int q = lane >> 4, l16 = lane & 15;
    const uint4* H4 = (const uint4*)H2;

    float a0 = 0.f, a1 = 0.f, a2 = 0.f, a3 = 0.f,
          a4 = 0.f, a5 = 0.f, a6 = 0.f, a7 = 0.f;
    if (q == 0) {                          // self-loop term (pre-scaled row)
        uint4 v = H4[(size_t)node * 16 + l16];
        ACC8_P(v);
    }

    int j = rowptr[node];
    const int end = rowptr[node + 1];
    for (; j + 8 <= end; j += 8) {
        int s0 = csr[j + q], s1 = csr[j + 4 + q];
        uint4 v0 = H4[(size_t)s0 * 16 + l16];
        uint4 v1 = H4[(size_t)s1 * 16 + l16];
        ACC8_P(v0); ACC8_P(v1);
    }
    if (j + 4 <= end) {
        int s = csr[j + q];
        uint4 v = H4[(size_t)s * 16 + l16];
        ACC8_P(v);
        j += 4;
    }
    if (q < end - j) {
        int s = csr[j + q];
        uint4 v = H4[(size_t)s * 16 + l16];
        ACC8_P(v);
    }

    a0 += __shfl_xor(a0, 16, 64); a1 += __shfl_xor(a1, 16, 64);
    a2 += __shfl_xor(a2, 16, 64); a3 += __shfl_xor(a3, 16, 64);
    a4 += __shfl_xor(a4, 16, 64); a5 += __shfl_xor(a5, 16, 64);
    a6 += __shfl_xor(a6, 16, 64); a7 += __shfl_xor(a7, 16, 64);
    a0 += __shfl_xor(a0, 32, 64); a1 += __shfl_xor(a1, 32, 64);
    a2 += __shfl_xor(a2, 32, 64); a3 += __shfl_xor(a3, 32, 64);
    a4 += __shfl_xor(a4, 32, 64); a5 += __shfl_xor(a5, 32, 64);
    a6 += __shfl_xor(a6, 32, 64); a7 += __shfl_xor(a7, 32, 64);

    if (lane < 16) {
        const float dn = dinv[node];
        float4 bbA = b4[l16 * 2], bbB = b4[l16 * 2 + 1];
        float4 oA, oB;
        oA.x = a0 * dn + bbA.x; oA.y = a1 * dn + bbA.y;
        oA.z = a2 * dn + bbA.z; oA.w = a3 * dn + bbA.w;
        oB.x = a4 * dn + bbB.x; oB.y = a5 * dn + bbB.y;
        oB.z = a6 * dn + bbB.z; oB.w = a7 * dn + bbB.w;
        out[(size_t)node * 32 + l16 * 2]     = oA;
        out[(size_t)node * 32 + l16 * 2 + 1] = oB;
    }
}

// ---------------- layer-2 GEMM: A pre-split, B direct from L2, 32KB LDS ----

__global__ __launch_bounds__(256) void gemm_xw2(const uint2* __restrict__ h1h,
                                                const uint2* __restrict__ h1l,
                                                const uint4* __restrict__ fWh,
                                                const uint4* __restrict__ fWl,
                                                uint2* __restrict__ O) {
    __shared__ __align__(16) char smem[32768];
    const int t = threadIdx.x;
    const int w = t >> 6, lane = t & 63;
    const int lrow = lane & 15, lgrp = lane >> 4;
    const int rbase = blockIdx.x * 128;

    bf16x8 Ah[2][4], Al[2][4];
    const bf16x8 zz = (bf16x8){0,0,0,0,0,0,0,0};
#pragma unroll
    for (int m = 0; m < 2; ++m) {
        const int r = rbase + w * 32 + m * 16 + lrow;
        const bool ok = (r < N_NODES);
        const uint2* ph = h1h + (size_t)r * 32 + lgrp * 2;
        const uint2* pl = h1l + (size_t)r * 32 + lgrp * 2;
#pragma unroll
        for (int q = 0; q < 4; ++q) {
            Ah[m][q] = ok ? *(const bf16x8*)(ph + q * 8) : zz;
            Al[m][q] = ok ? *(const bf16x8*)(pl + q * 8) : zz;
        }
    }

    f32x4 acc[2][8];
#pragma unroll
    for (int m = 0; m < 2; ++m)
#pragma unroll
        for (int c = 0; c < 8; ++c)
            acc[m][c] = (f32x4){0.f, 0.f, 0.f, 0.f};

    const bf16x8* Bh = (const bf16x8*)fWh;
    const bf16x8* Bl = (const bf16x8*)fWl;
#pragma unroll
    for (int c = 0; c < 8; ++c) {
#pragma unroll
        for (int q = 0; q < 4; ++q) {
            bf16x8 bh = Bh[(c * 4 + q) * 64 + lane];
            bf16x8 bl = Bl[(c * 4 + q) * 64 + lane];
#pragma unroll
            for (int m = 0; m < 2; ++m) {
                acc[m][c] = __builtin_amdgcn_mfma_f32_16x16x32_bf16(Ah[m][q], bh, acc[m][c], 0, 0, 0);
                acc[m][c] = __builtin_amdgcn_mfma_f32_16x16x32_bf16(Al[m][q], bh, acc[m][c], 0, 0, 0);
                acc[m][c] = __builtin_amdgcn_mfma_f32_16x16x32_bf16(Ah[m][q], bl, acc[m][c], 0, 0, 0);
            }
        }
    }

    float* Lf = (float*)smem;              // [64][128] fp32, two halves
#pragma unroll
    for (int m = 0; m < 2; ++m) {
        __syncthreads();
#pragma unroll
        for (int c = 0; c < 8; ++c)
#pragma unroll
            for (int rg = 0; rg < 4; ++rg)
                Lf[(w * 16 + lgrp * 4 + rg) * 128 + c * 16 + lrow] = acc[m][c][rg];
        __syncthreads();
        const float4* Lf4 = (const float4*)smem;
        for (int idx = t; idx < 2048; idx += 256) {
            const int rl = idx >> 5, s = idx & 31;
            const int gr = rbase + (rl >> 4) * 32 + m * 16 + (rl & 15);
            if (gr < N_NODES) {
                float4 v = Lf4[idx];
                uint2 o;
                o.x = pk_bf16(v.x, v.y);
                o.y = pk_bf16(v.z, v.w);
                O[(size_t)gr * 32 + s] = o;
            }
        }
    }
}

// ---------------- launch ----------------

extern "C" void kernel_launch(void* const* d_in, const int* in_sizes, int n_in,
                              void* d_out, int out_size, void* d_ws, size_t ws_size,
                              hipStream_t stream) {
    const float* x  = (const float*)d_in[0];
    const int*   ei = (const int*)d_in[1];
    const float* W1 = (const float*)d_in[2];
    const float* b1 = (const float*)d_in[3];
    const float* W2 = (const float*)d_in[4];
    const float* b2 = (const float*)d_in[5];
    float* out = (float*)d_out;

    const int* src = ei;             // edge_index[0]
    const int* dst = ei + N_EDGES;   // edge_index[1]

    char* p = (char*)d_ws;
    int*      chist  = (int*)p;              p += GRID * 256 * 4;              // 200 KB
    float*    dinv   = (float*)p;            p += ((N_NODES * 4 + 1023) & ~1023);
    int*      rowptr = (int*)p;              p += (((N_NODES + 1) * 4 + 1023) & ~1023);
    unsigned* sorted = (unsigned*)p;         p += ((N_EDGES * 4 + 1023) & ~1023);
    int*      csr    = (int*)p;              p += ((N_EDGES * 4 + 1023) & ~1023);
    int*      bbase  = (int*)p;              p += 1024;                        // 256 ints
    uint4*    f1h    = (uint4*)p;            p += 32768;                       // W1 hi frags
    uint4*    f1l    = (uint4*)p;            p += 32768;                       // W1 lo frags
    uint4*    f2h    = (uint4*)p;            p += 32768;                       // W2 hi frags
    uint4*    f2l    = (uint4*)p;            p += 32768;                       // W2 lo frags
    uint2*    hp     = (uint2*)p;            p += (size_t)N_NODES * DIM * 2;   // bf16 layer1 lin table
    uint2*    h1h    = (uint2*)p;            p += (size_t)N_NODES * DIM * 2;   // h1' hi bf16 (pre-scaled)
    uint2*    h1l    = (uint2*)p;            p += (size_t)N_NODES * DIM * 2;   // h1' lo bf16
    uint2*    hp2    = (uint2*)p;                                              // bf16 layer2 lin (pre-scaled)

    const int aggBlocks = (N_NODES + 3) / 4;     // 12500

    // ---- pass A + W-fragment build (co-gridded) ----
    chunk_hist_fragw<<<GRID + 16, 256, 0, stream>>>(dst, chist, W1, W2,
                                                    f1h, f1l, f2h, f2l);
    // ---- sort + ALL layer-1 gemm co-gridded (587 blocks, ~3/CU resident) ----
    sort_gemm<<<GRID + GA, 256, 0, stream>>>(src, dst, chist, sorted, bbase,
                                             x, f1h, f1l, hp);
    // ---- CSR finalize (196 blocks, 27.6 KB LDS -> 5/CU, all co-resident) ----
    csr_build<<<GRID, 256, 0, stream>>>(sorted, bbase, rowptr, dinv, csr);

    // ---- layer 1 aggregate (+b1, relu, pre-scale) -> h1' hi/lo ----
    aggregate_h1<<<aggBlocks, 256, 0, stream>>>(hp, rowptr, csr, dinv,
                                                (const float4*)b1,
                                                (uint4*)h1h, (uint4*)h1l);

    // ---- layer 2 MFMA GEMM (pre-split A) -> hp2 (pre-scaled rows) ----
    gemm_xw2<<<GEMM_BLOCKS, 256, 0, stream>>>(h1h, h1l, f2h, f2l, hp2);

    // ---- final aggregate (plain adds) -> out ----
    aggregate_out<<<aggBlocks, 256, 0, stream>>>(hp2, rowptr, csr, dinv,
                                                 (const float4*)b2, (float4*)out);
}

// Round 10
// 198.177 us; speedup vs baseline: 1.0435x; 1.0435x over previous
//
#include <hip/hip_runtime.h>

#define N_NODES 50000
#define N_EDGES 800000
#define DIM 128
#define CHUNK 4096      // edges per chunk; 196*4096 >= 800000
#define GRID 196        // chunks == buckets == blocks for build passes
#define SEG_CAP 6144    // LDS csr segment cap (mean 4096, sigma 64)
#define GEMM_BLOCKS 391 // ceil(50000/128) -- 128 rows per block
#define GA 391          // ALL layer-1 gemm blocks co-gridded with sort

typedef __attribute__((ext_vector_type(8))) short bf16x8;   // 8 bf16 = 4 VGPRs
typedef __attribute__((ext_vector_type(4))) float f32x4;    // MFMA acc

// ---------------- bf16 pack/unpack (RNE) ----------------

__device__ inline unsigned rne_bf16(float f) {
    unsigned u = __float_as_uint(f);
    return (u + 0x7FFFu + ((u >> 16) & 1u)) >> 16;
}
__device__ inline unsigned pk_bf16(float a, float b) {
    return rne_bf16(a) | (rne_bf16(b) << 16);
}
__device__ inline float bf_lo(unsigned u) { return __uint_as_float(u << 16); }
__device__ inline float bf_hi(unsigned u) { return __uint_as_float(u & 0xFFFF0000u); }

// ---------------- W -> MFMA fragment pre-pass (bf16 hi/lo split) -----------

__device__ void fragw_build(const float* __restrict__ W, uint4* __restrict__ fh,
                            uint4* __restrict__ fl, int slot) {
    const int lane = slot & 63, tile = slot >> 6;     // tile 0..31
    const int c = tile >> 2, q = tile & 3;
    const int k0 = q * 32 + ((lane >> 4) << 3);
    const int col = c * 16 + (lane & 15);
    unsigned h[8], l[8];
#pragma unroll
    for (int j = 0; j < 8; ++j) {
        float w = W[(size_t)(k0 + j) * DIM + col];
        unsigned hb = rne_bf16(w);
        h[j] = hb;
        l[j] = rne_bf16(w - __uint_as_float(hb << 16));
    }
    uint4 uh, ul;
    uh.x = h[0] | (h[1] << 16); uh.y = h[2] | (h[3] << 16);
    uh.z = h[4] | (h[5] << 16); uh.w = h[6] | (h[7] << 16);
    ul.x = l[0] | (l[1] << 16); ul.y = l[2] | (l[3] << 16);
    ul.z = l[4] | (l[5] << 16); ul.w = l[6] | (l[7] << 16);
    fh[slot] = uh;
    fl[slot] = ul;
}

// ---------------- Pass A + fragW: co-gridded ----------------

__global__ __launch_bounds__(256) void chunk_hist_fragw(const int* __restrict__ dst,
                                                        int* __restrict__ chist,
                                                        const float* __restrict__ W1,
                                                        const float* __restrict__ W2,
                                                        uint4* f1h, uint4* f1l,
                                                        uint4* f2h, uint4* f2l) {
    const int bid = blockIdx.x;
    if (bid < GRID) {
        __shared__ int hist[256];
        const int t = threadIdx.x;
        const int eb = bid * CHUNK;
        const int cnt = min(CHUNK, N_EDGES - eb);
        hist[t] = 0;
        __syncthreads();
        for (int i = t; i < cnt; i += 256)
            atomicAdd(&hist[dst[eb + i] >> 8], 1);
        __syncthreads();
        chist[bid * 256 + t] = hist[t];
    } else {
        const int b2 = bid - GRID;                    // 0..15
        const int slot = (b2 & 7) * 256 + threadIdx.x; // 0..2047
        if (b2 < 8) fragw_build(W1, f1h, f1l, slot);
        else        fragw_build(W2, f2h, f2l, slot);
    }
}

// ---------------- MFMA GEMM body: staged-B (round-8 verified) --------------

__device__ void gemm_body(const float* __restrict__ X,
                          const uint4* __restrict__ fWh,
                          const uint4* __restrict__ fWl,
                          uint2* __restrict__ O, int gb, char* smem) {
    const int t = threadIdx.x;

    {   // stage W fragments: hi at [0,32KB), lo at [32KB,64KB)
        uint4* s4 = (uint4*)smem;
        for (int i = t; i < 2048; i += 256) {
            s4[i] = fWh[i];
            s4[2048 + i] = fWl[i];
        }
    }
    __syncthreads();

    const int w = t >> 6, lane = t & 63;
    const int lrow = lane & 15, lgrp = lane >> 4;
    const int rbase = gb * 128;

    bf16x8 Ah[2][4], Al[2][4];
#pragma unroll
    for (int m = 0; m < 2; ++m) {
        const int r = rbase + w * 32 + m * 16 + lrow;
        const bool ok = (r < N_NODES);
        const float4* xp = (const float4*)(X + (size_t)r * DIM + lgrp * 8);
#pragma unroll
        for (int q = 0; q < 4; ++q) {
            float4 a0 = ok ? xp[q * 8]     : make_float4(0.f, 0.f, 0.f, 0.f);
            float4 a1 = ok ? xp[q * 8 + 1] : make_float4(0.f, 0.f, 0.f, 0.f);
            float f[8] = {a0.x, a0.y, a0.z, a0.w, a1.x, a1.y, a1.z, a1.w};
            bf16x8 hi, lo;
#pragma unroll
            for (int j = 0; j < 8; ++j) {
                unsigned hb = rne_bf16(f[j]);
                hi[j] = (short)hb;
                lo[j] = (short)rne_bf16(f[j] - __uint_as_float(hb << 16));
            }
            Ah[m][q] = hi;
            Al[m][q] = lo;
        }
    }

    f32x4 acc[2][8];
#pragma unroll
    for (int m = 0; m < 2; ++m)
#pragma unroll
        for (int c = 0; c < 8; ++c)
            acc[m][c] = (f32x4){0.f, 0.f, 0.f, 0.f};

    const bf16x8* Bh = (const bf16x8*)smem;
    const bf16x8* Bl = (const bf16x8*)(smem + 32768);
#pragma unroll
    for (int c = 0; c < 8; ++c) {
#pragma unroll
        for (int q = 0; q < 4; ++q) {
            bf16x8 bh = Bh[(c * 4 + q) * 64 + lane];
            bf16x8 bl = Bl[(c * 4 + q) * 64 + lane];
#pragma unroll
            for (int m = 0; m < 2; ++m) {
                acc[m][c] = __builtin_amdgcn_mfma_f32_16x16x32_bf16(Ah[m][q], bh, acc[m][c], 0, 0, 0);
                acc[m][c] = __builtin_amdgcn_mfma_f32_16x16x32_bf16(Al[m][q], bh, acc[m][c], 0, 0, 0);
                acc[m][c] = __builtin_amdgcn_mfma_f32_16x16x32_bf16(Ah[m][q], bl, acc[m][c], 0, 0, 0);
            }
        }
    }

    __syncthreads();
    float* Lf = (float*)smem;
#pragma unroll
    for (int m = 0; m < 2; ++m)
#pragma unroll
        for (int c = 0; c < 8; ++c)
#pragma unroll
            for (int rg = 0; rg < 4; ++rg)
                Lf[(w * 32 + m * 16 + lgrp * 4 + rg) * DIM + c * 16 + lrow] = acc[m][c][rg];
    __syncthreads();

    const float4* Lf4 = (const float4*)smem;
    for (int idx = t; idx < 4096; idx += 256) {
        const int row = idx >> 5, s = idx & 31;
        const int gr = rbase + row;
        if (gr < N_NODES) {
            float4 v = Lf4[idx];
            uint2 o;
            o.x = pk_bf16(v.x, v.y);
            o.y = pk_bf16(v.z, v.w);
            O[(size_t)gr * 32 + s] = o;
        }
    }
}

// ---------------- Pass B body: counting sort; offsets from chist -----------

__device__ void sort_scatter_body(const int* __restrict__ src,
                                  const int* __restrict__ dst,
                                  const int* __restrict__ chist,
                                  unsigned* __restrict__ sorted,
                                  int* __restrict__ bbase_g,
                                  int bid, char* smem) {
    int* hist  = (int*)smem;
    int* sc    = hist + 256;
    int* lbase = sc + 256;
    int* lcur  = lbase + 256;
    int* gbase = lcur + 256;
    unsigned* sl = (unsigned*)(smem + 5 * 1024);   // CHUNK entries

    const int t = threadIdx.x;
    const int eb = bid * CHUNK;
    const int cnt = min(CHUNK, N_EDGES - eb);

    int sum = 0, myoff = 0;
    for (int c = 0; c < GRID; ++c) {
        int v = chist[c * 256 + t];
        if (c == bid) myoff = sum;
        sum += v;
    }
    hist[t] = chist[bid * 256 + t];
    sc[t] = sum;
    __syncthreads();
    for (int off = 1; off < 256; off <<= 1) {
        int u = (t >= off) ? sc[t - off] : 0;
        __syncthreads();
        sc[t] += u;
        __syncthreads();
    }
    gbase[t] = (sc[t] - sum) + myoff;
    if (bid == 0) bbase_g[t] = sc[t] - sum;   // exclusive scan of bucket totals
    __syncthreads();

    sc[t] = hist[t];
    __syncthreads();
    for (int off = 1; off < 256; off <<= 1) {
        int u = (t >= off) ? sc[t - off] : 0;
        __syncthreads();
        sc[t] += u;
        __syncthreads();
    }
    int ex = sc[t] - hist[t];
    lbase[t] = ex;
    lcur[t] = ex;
    __syncthreads();

    for (int i = t; i < cnt; i += 256) {
        int s = src[eb + i], d = dst[eb + i];
        int b = d >> 8;
        int p = atomicAdd(&lcur[b], 1);
        sl[p] = ((unsigned)b << 24) | ((unsigned)(d & 255) << 16) | (unsigned)s;
    }
    __syncthreads();
    for (int i = t; i < cnt; i += 256) {
        unsigned rec = sl[i];
        int b = rec >> 24;
        sorted[gbase[b] + (i - lbase[b])] = rec;
    }
}

// ---------------- Fused dispatch: sort blocks first, ALL gemm1 backfills ---

__global__ __launch_bounds__(256, 2) void sort_gemm(const int* __restrict__ src,
                                                    const int* __restrict__ dst,
                                                    const int* __restrict__ chist,
                                                    unsigned* __restrict__ sorted,
                                                    int* __restrict__ bbase_g,
                                                    const float* __restrict__ X,
                                                    const uint4* __restrict__ fWh,
                                                    const uint4* __restrict__ fWl,
                                                    uint2* __restrict__ O) {
    __shared__ __align__(16) char smem[65536];
    if (blockIdx.x < GRID)
        sort_scatter_body(src, dst, chist, sorted, bbase_g, blockIdx.x, smem);
    else
        gemm_body(X, fWh, fWl, O, blockIdx.x - GRID, smem);
}

// ---------------- Pass C: per-bucket CSR finalize (standalone, 5/CU) -------

__global__ __launch_bounds__(256) void csr_build(const unsigned* __restrict__ sorted,
                                                 const int* __restrict__ bbase,
                                                 int* __restrict__ rowptr,
                                                 float* __restrict__ dinv,
                                                 int* __restrict__ csr) {
    __shared__ __align__(16) char smem[3 * 1024 + SEG_CAP * 4];   // 27.6 KB
    int* hist = (int*)smem;
    int* sc   = hist + 256;
    int* lcur = sc + 256;
    int* seg  = (int*)(smem + 3 * 1024);

    const int k = blockIdx.x;
    const int t = threadIdx.x;
    const int base = bbase[k];
    const int cntk = ((k == 255) ? N_EDGES : bbase[k + 1]) - base;
    if (k == 0 && t == 0) rowptr[N_NODES] = N_EDGES;

    hist[t] = 0;
    __syncthreads();
    for (int i = t; i < cntk; i += 256)
        atomicAdd(&hist[(sorted[base + i] >> 16) & 255], 1);
    __syncthreads();

    const int node = (k << 8) + t;
    const int dv = hist[t];
    if (node < N_NODES) dinv[node] = rsqrtf((float)dv + 1.0f);   // +1 self-loop

    sc[t] = dv;
    __syncthreads();
    for (int off = 1; off < 256; off <<= 1) {
        int u = (t >= off) ? sc[t - off] : 0;
        __syncthreads();
        sc[t] += u;
        __syncthreads();
    }
    int ex = sc[t] - dv;
    if (node < N_NODES) rowptr[node] = base + ex;
    lcur[t] = ex;
    __syncthreads();

    if (cntk <= SEG_CAP) {
        for (int i = t; i < cntk; i += 256) {
            unsigned rec = sorted[base + i];
            int p = atomicAdd(&lcur[(rec >> 16) & 255], 1);
            seg[p] = (int)(rec & 0xFFFFu);
        }
        __syncthreads();
        for (int i = t; i < cntk; i += 256)
            csr[base + i] = seg[i];
    } else {
        for (int i = t; i < cntk; i += 256) {
            unsigned rec = sorted[base + i];
            int p = atomicAdd(&lcur[(rec >> 16) & 255], 1);
            csr[base + p] = (int)(rec & 0xFFFFu);
        }
    }
}

// ---------------- quarter-wave aggregation (uint4 = 16B/lane gathers) ------

#define ACC8_D(v, d) do { \
        a0 = fmaf((d), bf_lo((v).x), a0); a1 = fmaf((d), bf_hi((v).x), a1); \
        a2 = fmaf((d), bf_lo((v).y), a2); a3 = fmaf((d), bf_hi((v).y), a3); \
        a4 = fmaf((d), bf_lo((v).z), a4); a5 = fmaf((d), bf_hi((v).z), a5); \
        a6 = fmaf((d), bf_lo((v).w), a6); a7 = fmaf((d), bf_hi((v).w), a7); } while (0)

#define ACC8_P(v) do { \
        a0 += bf_lo((v).x); a1 += bf_hi((v).x); \
        a2 += bf_lo((v).y); a3 += bf_hi((v).y); \
        a4 += bf_lo((v).z); a5 += bf_hi((v).z); \
        a6 += bf_lo((v).w); a7 += bf_hi((v).w); } while (0)

// ---------------- layer-1 aggregate: per-edge dinv fmaf; writes h1' hi/lo --
// h1' = dinv[n] * relu(agg*dn + b1)  -> pre-scaled for layer 2 (linearity).

__global__ __launch_bounds__(256) void aggregate_h1(const uint2* __restrict__ H2,
                                                    const int* __restrict__ rowptr,
                                                    const int* __restrict__ csr,
                                                    const float* __restrict__ dinv,
                                                    const float4* __restrict__ b4,
                                                    uint4* __restrict__ h1h4,
                                                    uint4* __restrict__ h1l4) {
    const int node = blockIdx.x * 4 + (threadIdx.x >> 6);
    if (node >= N_NODES) return;
    const int lane = threadIdx.x & 63;
    const int q = lane >> 4, l16 = lane & 15;
    const uint4* H4 = (const uint4*)H2;

    const float dn = dinv[node];
    float a0 = 0.f, a1 = 0.f, a2 = 0.f, a3 = 0.f,
          a4 = 0.f, a5 = 0.f, a6 = 0.f, a7 = 0.f;
    if (q == 0) {                          // self-loop term: weight dinv[node]
        uint4 v = H4[(size_t)node * 16 + l16];
        ACC8_D(v, dn);
    }

    int j = rowptr[node];
    const int end = rowptr[node + 1];
    for (; j + 8 <= end; j += 8) {         // 2 gathers in flight per quarter
        int s0 = csr[j + q], s1 = csr[j + 4 + q];
        uint4 v0 = H4[(size_t)s0 * 16 + l16]; float d0 = dinv[s0];
        uint4 v1 = H4[(size_t)s1 * 16 + l16]; float d1 = dinv[s1];
        ACC8_D(v0, d0); ACC8_D(v1, d1);
    }
    if (j + 4 <= end) {
        int s = csr[j + q];
        uint4 v = H4[(size_t)s * 16 + l16]; float d = dinv[s];
        ACC8_D(v, d);
        j += 4;
    }
    if (q < end - j) {
        int s = csr[j + q];
        uint4 v = H4[(size_t)s * 16 + l16]; float d = dinv[s];
        ACC8_D(v, d);
    }

    a0 += __shfl_xor(a0, 16, 64); a1 += __shfl_xor(a1, 16, 64);
    a2 += __shfl_xor(a2, 16, 64); a3 += __shfl_xor(a3, 16, 64);
    a4 += __shfl_xor(a4, 16, 64); a5 += __shfl_xor(a5, 16, 64);
    a6 += __shfl_xor(a6, 16, 64); a7 += __shfl_xor(a7, 16, 64);
    a0 += __shfl_xor(a0, 32, 64); a1 += __shfl_xor(a1, 32, 64);
    a2 += __shfl_xor(a2, 32, 64); a3 += __shfl_xor(a3, 32, 64);
    a4 += __shfl_xor(a4, 32, 64); a5 += __shfl_xor(a5, 32, 64);
    a6 += __shfl_xor(a6, 32, 64); a7 += __shfl_xor(a7, 32, 64);

    if (lane < 16) {
        float4 bbA = b4[l16 * 2], bbB = b4[l16 * 2 + 1];
        float o0 = fmaxf(a0 * dn + bbA.x, 0.f), o1 = fmaxf(a1 * dn + bbA.y, 0.f);
        float o2 = fmaxf(a2 * dn + bbA.z, 0.f), o3 = fmaxf(a3 * dn + bbA.w, 0.f);
        float o4 = fmaxf(a4 * dn + bbB.x, 0.f), o5 = fmaxf(a5 * dn + bbB.y, 0.f);
        float o6 = fmaxf(a6 * dn + bbB.z, 0.f), o7 = fmaxf(a7 * dn + bbB.w, 0.f);
        o0 *= dn; o1 *= dn; o2 *= dn; o3 *= dn;
        o4 *= dn; o5 *= dn; o6 *= dn; o7 *= dn;
        unsigned h0 = rne_bf16(o0), h1 = rne_bf16(o1), h2 = rne_bf16(o2), h3 = rne_bf16(o3);
        unsigned h4 = rne_bf16(o4), h5 = rne_bf16(o5), h6 = rne_bf16(o6), h7 = rne_bf16(o7);
        uint4 hv;
        hv.x = h0 | (h1 << 16); hv.y = h2 | (h3 << 16);
        hv.z = h4 | (h5 << 16); hv.w = h6 | (h7 << 16);
        uint4 lv;
        lv.x = rne_bf16(o0 - __uint_as_float(h0 << 16)) |
               (rne_bf16(o1 - __uint_as_float(h1 << 16)) << 16);
        lv.y = rne_bf16(o2 - __uint_as_float(h2 << 16)) |
               (rne_bf16(o3 - __uint_as_float(h3 << 16)) << 16);
        lv.z = rne_bf16(o4 - __uint_as_float(h4 << 16)) |
               (rne_bf16(o5 - __uint_as_float(h5 << 16)) << 16);
        lv.w = rne_bf16(o6 - __uint_as_float(h6 << 16)) |
               (rne_bf16(o7 - __uint_as_float(h7 << 16)) << 16);
        h1h4[(size_t)node * 16 + l16] = hv;
        h1l4[(size_t)node * 16 + l16] = lv;
    }
}

// ---------------- final aggregate: hp2 pre-scaled -> plain adds ------------

__global__ __launch_bounds__(256) void aggregate_out(const uint2* __restrict__ H2,
                                                     const int* __restrict__ rowptr,
                                                     const int* __restrict__ csr,
                                                     const float* __restrict__ dinv,
                                                     const float4* __restrict__ b4,
                                                     float4* __restrict__ out) {
    const int node = blockIdx.x * 4 + (threadIdx.x >> 6);
    if (node >= N_NODES) return;
    const int lane = threadIdx.x & 63;
    const int q = lane >> 4, l16 = lane & 15;
    const uint4* H4 = (const uint4*)H2;

    float a0 = 0.f, a1 = 0.f, a2 = 0.f, a3 = 0.f,
          a4 = 0.f, a5 = 0.f, a6 = 0.f, a7 = 0.f;
    if (q == 0) {                          // self-loop term (pre-scaled row)
        uint4 v = H4[(size_t)node * 16 + l16];
        ACC8_P(v);
    }

    int j = rowptr[node];
    const int end = rowptr[node + 1];
    for (; j + 8 <= end; j += 8) {
        int s0 = csr[j + q], s1 = csr[j + 4 + q];
        uint4 v0 = H4[(size_t)s0 * 16 + l16];
        uint4 v1 = H4[(size_t)s1 * 16 + l16];
        ACC8_P(v0); ACC8_P(v1);
    }
    if (j + 4 <= end) {
        int s = csr[j + q];
        uint4 v = H4[(size_t)s * 16 + l16];
        ACC8_P(v);
        j += 4;
    }
    if (q < end - j) {
        int s = csr[j + q];
        uint4 v = H4[(size_t)s * 16 + l16];
        ACC8_P(v);
    }

    a0 += __shfl_xor(a0, 16, 64); a1 += __shfl_xor(a1, 16, 64);
    a2 += __shfl_xor(a2, 16, 64); a3 += __shfl_xor(a3, 16, 64);
    a4 += __shfl_xor(a4, 16, 64); a5 += __shfl_xor(a5, 16, 64);
    a6 += __shfl_xor(a6, 16, 64); a7 += __shfl_xor(a7, 16, 64);
    a0 += __shfl_xor(a0, 32, 64); a1 += __shfl_xor(a1, 32, 64);
    a2 += __shfl_xor(a2, 32, 64); a3 += __shfl_xor(a3, 32, 64);
    a4 += __shfl_xor(a4, 32, 64); a5 += __shfl_xor(a5, 32, 64);
    a6 += __shfl_xor(a6, 32, 64); a7 += __shfl_xor(a7, 32, 64);

    if (lane < 16) {
        const float dn = dinv[node];
        float4 bbA = b4[l16 * 2], bbB = b4[l16 * 2 + 1];
        float4 oA, oB;
        oA.x = a0 * dn + bbA.x; oA.y = a1 * dn + bbA.y;
        oA.z = a2 * dn + bbA.z; oA.w = a3 * dn + bbA.w;
        oB.x = a4 * dn + bbB.x; oB.y = a5 * dn + bbB.y;
        oB.z = a6 * dn + bbB.z; oB.w = a7 * dn + bbB.w;
        out[(size_t)node * 32 + l16 * 2]     = oA;
        out[(size_t)node * 32 + l16 * 2 + 1] = oB;
    }
}

// ---------------- layer-2 GEMM: A pre-split bf16 hi/lo, staged B -----------

__global__ __launch_bounds__(256, 2) void gemm_xw2(const uint2* __restrict__ h1h,
                                                   const uint2* __restrict__ h1l,
                                                   const uint4* __restrict__ fWh,
                                                   const uint4* __restrict__ fWl,
                                                   uint2* __restrict__ O) {
    __shared__ __align__(16) char smem[65536];
    const int t = threadIdx.x;

    {   // stage W fragments: hi at [0,32KB), lo at [32KB,64KB)
        uint4* s4 = (uint4*)smem;
        for (int i = t; i < 2048; i += 256) {
            s4[i] = fWh[i];
            s4[2048 + i] = fWl[i];
        }
    }
    __syncthreads();

    const int w = t >> 6, lane = t & 63;
    const int lrow = lane & 15, lgrp = lane >> 4;
    const int rbase = blockIdx.x * 128;

    bf16x8 Ah[2][4], Al[2][4];
    const bf16x8 zz = (bf16x8){0,0,0,0,0,0,0,0};
#pragma unroll
    for (int m = 0; m < 2; ++m) {
        const int r = rbase + w * 32 + m * 16 + lrow;
        const bool ok = (r < N_NODES);
        const uint2* ph = h1h + (size_t)r * 32 + lgrp * 2;
        const uint2* pl = h1l + (size_t)r * 32 + lgrp * 2;
#pragma unroll
        for (int q = 0; q < 4; ++q) {
            Ah[m][q] = ok ? *(const bf16x8*)(ph + q * 8) : zz;
            Al[m][q] = ok ? *(const bf16x8*)(pl + q * 8) : zz;
        }
    }

    f32x4 acc[2][8];
#pragma unroll
    for (int m = 0; m < 2; ++m)
#pragma unroll
        for (int c = 0; c < 8; ++c)
            acc[m][c] = (f32x4){0.f, 0.f, 0.f, 0.f};

    const bf16x8* Bh = (const bf16x8*)smem;
    const bf16x8* Bl = (const bf16x8*)(smem + 32768);
#pragma unroll
    for (int c = 0; c < 8; ++c) {
#pragma unroll
        for (int q = 0; q < 4; ++q) {
            bf16x8 bh = Bh[(c * 4 + q) * 64 + lane];
            bf16x8 bl = Bl[(c * 4 + q) * 64 + lane];
#pragma unroll
            for (int m = 0; m < 2; ++m) {
                acc[m][c] = __builtin_amdgcn_mfma_f32_16x16x32_bf16(Ah[m][q], bh, acc[m][c], 0, 0, 0);
                acc[m][c] = __builtin_amdgcn_mfma_f32_16x16x32_bf16(Al[m][q], bh, acc[m][c], 0, 0, 0);
                acc[m][c] = __builtin_amdgcn_mfma_f32_16x16x32_bf16(Ah[m][q], bl, acc[m][c], 0, 0, 0);
            }
        }
    }

    __syncthreads();
    float* Lf = (float*)smem;
#pragma unroll
    for (int m = 0; m < 2; ++m)
#pragma unroll
        for (int c = 0; c < 8; ++c)
#pragma unroll
            for (int rg = 0; rg < 4; ++rg)
                Lf[(w * 32 + m * 16 + lgrp * 4 + rg) * DIM + c * 16 + lrow] = acc[m][c][rg];
    __syncthreads();

    const float4* Lf4 = (const float4*)smem;
    for (int idx = t; idx < 4096; idx += 256) {
        const int row = idx >> 5, s = idx & 31;
        const int gr = rbase + row;
        if (gr < N_NODES) {
            float4 v = Lf4[idx];
            uint2 o;
            o.x = pk_bf16(v.x, v.y);
            o.y = pk_bf16(v.z, v.w);
            O[(size_t)gr * 32 + s] = o;
        }
    }
}

// ---------------- launch ----------------

extern "C" void kernel_launch(void* const* d_in, const int* in_sizes, int n_in,
                              void* d_out, int out_size, void* d_ws, size_t ws_size,
                              hipStream_t stream) {
    const float* x  = (const float*)d_in[0];
    const int*   ei = (const int*)d_in[1];
    const float* W1 = (const float*)d_in[2];
    const float* b1 = (const float*)d_in[3];
    const float* W2 = (const float*)d_in[4];
    const float* b2 = (const float*)d_in[5];
    float* out = (float*)d_out;

    const int* src = ei;             // edge_index[0]
    const int* dst = ei + N_EDGES;   // edge_index[1]

    char* p = (char*)d_ws;
    int*      chist  = (int*)p;              p += GRID * 256 * 4;              // 200 KB
    float*    dinv   = (float*)p;            p += ((N_NODES * 4 + 1023) & ~1023);
    int*      rowptr = (int*)p;              p += (((N_NODES + 1) * 4 + 1023) & ~1023);
    unsigned* sorted = (unsigned*)p;         p += ((N_EDGES * 4 + 1023) & ~1023);
    int*      csr    = (int*)p;              p += ((N_EDGES * 4 + 1023) & ~1023);
    int*      bbase  = (int*)p;              p += 1024;                        // 256 ints
    uint4*    f1h    = (uint4*)p;            p += 32768;                       // W1 hi frags
    uint4*    f1l    = (uint4*)p;            p += 32768;                       // W1 lo frags
    uint4*    f2h    = (uint4*)p;            p += 32768;                       // W2 hi frags
    uint4*    f2l    = (uint4*)p;            p += 32768;                       // W2 lo frags
    uint2*    hp     = (uint2*)p;            p += (size_t)N_NODES * DIM * 2;   // bf16 layer1 lin table
    uint2*    h1h    = (uint2*)p;            p += (size_t)N_NODES * DIM * 2;   // h1' hi bf16 (pre-scaled)
    uint2*    h1l    = (uint2*)p;            p += (size_t)N_NODES * DIM * 2;   // h1' lo bf16
    uint2*    hp2    = (uint2*)p;                                              // bf16 layer2 lin (pre-scaled)

    const int aggBlocks = (N_NODES + 3) / 4;     // 12500

    // ---- pass A + W-fragment build (co-gridded) ----
    chunk_hist_fragw<<<GRID + 16, 256, 0, stream>>>(dst, chist, W1, W2,
                                                    f1h, f1l, f2h, f2l);
    // ---- sort + ALL layer-1 gemm co-gridded (587 blocks; staged-B gemm) ----
    sort_gemm<<<GRID + GA, 256, 0, stream>>>(src, dst, chist, sorted, bbase,
                                             x, f1h, f1l, hp);
    // ---- CSR finalize (196 blocks, 27.6 KB LDS -> 5/CU, all co-resident) ----
    csr_build<<<GRID, 256, 0, stream>>>(sorted, bbase, rowptr, dinv, csr);

    // ---- layer 1 aggregate (+b1, relu, pre-scale) -> h1' hi/lo ----
    aggregate_h1<<<aggBlocks, 256, 0, stream>>>(hp, rowptr, csr, dinv,
                                                (const float4*)b1,
                                                (uint4*)h1h, (uint4*)h1l);

    // ---- layer 2 MFMA GEMM (pre-split A, staged B) -> hp2 ----
    gemm_xw2<<<GEMM_BLOCKS, 256, 0, stream>>>(h1h, h1l, f2h, f2l, hp2);

    // ---- final aggregate (plain adds) -> out ----
    aggregate_out<<<aggBlocks, 256, 0, stream>>>(hp2, rowptr, csr, dinv,
                                                 (const float4*)b2, (float4*)out);
}

// Round 11
// 196.977 us; speedup vs baseline: 1.0498x; 1.0061x over previous
//
#include <hip/hip_runtime.h>

#define N_NODES 50000
#define N_EDGES 800000
#define DIM 128
#define CHUNK 4096      // edges per chunk; 196*4096 >= 800000
#define GRID 196        // chunks == buckets == blocks for build passes
#define SEG_CAP 6144    // LDS csr segment cap (mean 4096, sigma 64)
#define GEMM_BLOCKS 391 // ceil(50000/128) -- 128 rows per block
#define GA 391          // ALL layer-1 gemm blocks co-gridded with sort

typedef __attribute__((ext_vector_type(8))) short bf16x8;   // 8 bf16 = 4 VGPRs
typedef __attribute__((ext_vector_type(4))) float f32x4;    // MFMA acc

// ---------------- bf16 pack/unpack (RNE) ----------------

__device__ inline unsigned rne_bf16(float f) {
    unsigned u = __float_as_uint(f);
    return (u + 0x7FFFu + ((u >> 16) & 1u)) >> 16;
}
__device__ inline unsigned pk_bf16(float a, float b) {
    return rne_bf16(a) | (rne_bf16(b) << 16);
}
__device__ inline float bf_lo(unsigned u) { return __uint_as_float(u << 16); }
__device__ inline float bf_hi(unsigned u) { return __uint_as_float(u & 0xFFFF0000u); }

// ---------------- W -> MFMA fragment pre-pass (bf16 hi/lo split) -----------

__device__ void fragw_build(const float* __restrict__ W, uint4* __restrict__ fh,
                            uint4* __restrict__ fl, int slot) {
    const int lane = slot & 63, tile = slot >> 6;     // tile 0..31
    const int c = tile >> 2, q = tile & 3;
    const int k0 = q * 32 + ((lane >> 4) << 3);
    const int col = c * 16 + (lane & 15);
    unsigned h[8], l[8];
#pragma unroll
    for (int j = 0; j < 8; ++j) {
        float w = W[(size_t)(k0 + j) * DIM + col];
        unsigned hb = rne_bf16(w);
        h[j] = hb;
        l[j] = rne_bf16(w - __uint_as_float(hb << 16));
    }
    uint4 uh, ul;
    uh.x = h[0] | (h[1] << 16); uh.y = h[2] | (h[3] << 16);
    uh.z = h[4] | (h[5] << 16); uh.w = h[6] | (h[7] << 16);
    ul.x = l[0] | (l[1] << 16); ul.y = l[2] | (l[3] << 16);
    ul.z = l[4] | (l[5] << 16); ul.w = l[6] | (l[7] << 16);
    fh[slot] = uh;
    fl[slot] = ul;
}

// ---------------- Pass A + fragW: co-gridded ----------------

__global__ __launch_bounds__(256) void chunk_hist_fragw(const int* __restrict__ dst,
                                                        int* __restrict__ chist,
                                                        const float* __restrict__ W1,
                                                        const float* __restrict__ W2,
                                                        uint4* f1h, uint4* f1l,
                                                        uint4* f2h, uint4* f2l) {
    const int bid = blockIdx.x;
    if (bid < GRID) {
        __shared__ int hist[256];
        const int t = threadIdx.x;
        const int eb = bid * CHUNK;
        const int cnt = min(CHUNK, N_EDGES - eb);
        hist[t] = 0;
        __syncthreads();
        for (int i = t; i < cnt; i += 256)
            atomicAdd(&hist[dst[eb + i] >> 8], 1);
        __syncthreads();
        chist[bid * 256 + t] = hist[t];
    } else {
        const int b2 = bid - GRID;                    // 0..15
        const int slot = (b2 & 7) * 256 + threadIdx.x; // 0..2047
        if (b2 < 8) fragw_build(W1, f1h, f1l, slot);
        else        fragw_build(W2, f2h, f2l, slot);
    }
}

// ---------------- MFMA GEMM body: staged-B (round-8 verified) --------------

__device__ void gemm_body(const float* __restrict__ X,
                          const uint4* __restrict__ fWh,
                          const uint4* __restrict__ fWl,
                          uint2* __restrict__ O, int gb, char* smem) {
    const int t = threadIdx.x;

    {   // stage W fragments: hi at [0,32KB), lo at [32KB,64KB)
        uint4* s4 = (uint4*)smem;
        for (int i = t; i < 2048; i += 256) {
            s4[i] = fWh[i];
            s4[2048 + i] = fWl[i];
        }
    }
    __syncthreads();

    const int w = t >> 6, lane = t & 63;
    const int lrow = lane & 15, lgrp = lane >> 4;
    const int rbase = gb * 128;

    bf16x8 Ah[2][4], Al[2][4];
#pragma unroll
    for (int m = 0; m < 2; ++m) {
        const int r = rbase + w * 32 + m * 16 + lrow;
        const bool ok = (r < N_NODES);
        const float4* xp = (const float4*)(X + (size_t)r * DIM + lgrp * 8);
#pragma unroll
        for (int q = 0; q < 4; ++q) {
            float4 a0 = ok ? xp[q * 8]     : make_float4(0.f, 0.f, 0.f, 0.f);
            float4 a1 = ok ? xp[q * 8 + 1] : make_float4(0.f, 0.f, 0.f, 0.f);
            float f[8] = {a0.x, a0.y, a0.z, a0.w, a1.x, a1.y, a1.z, a1.w};
            bf16x8 hi, lo;
#pragma unroll
            for (int j = 0; j < 8; ++j) {
                unsigned hb = rne_bf16(f[j]);
                hi[j] = (short)hb;
                lo[j] = (short)rne_bf16(f[j] - __uint_as_float(hb << 16));
            }
            Ah[m][q] = hi;
            Al[m][q] = lo;
        }
    }

    f32x4 acc[2][8];
#pragma unroll
    for (int m = 0; m < 2; ++m)
#pragma unroll
        for (int c = 0; c < 8; ++c)
            acc[m][c] = (f32x4){0.f, 0.f, 0.f, 0.f};

    const bf16x8* Bh = (const bf16x8*)smem;
    const bf16x8* Bl = (const bf16x8*)(smem + 32768);
#pragma unroll
    for (int c = 0; c < 8; ++c) {
#pragma unroll
        for (int q = 0; q < 4; ++q) {
            bf16x8 bh = Bh[(c * 4 + q) * 64 + lane];
            bf16x8 bl = Bl[(c * 4 + q) * 64 + lane];
#pragma unroll
            for (int m = 0; m < 2; ++m) {
                acc[m][c] = __builtin_amdgcn_mfma_f32_16x16x32_bf16(Ah[m][q], bh, acc[m][c], 0, 0, 0);
                acc[m][c] = __builtin_amdgcn_mfma_f32_16x16x32_bf16(Al[m][q], bh, acc[m][c], 0, 0, 0);
                acc[m][c] = __builtin_amdgcn_mfma_f32_16x16x32_bf16(Ah[m][q], bl, acc[m][c], 0, 0, 0);
            }
        }
    }

    __syncthreads();
    float* Lf = (float*)smem;
#pragma unroll
    for (int m = 0; m < 2; ++m)
#pragma unroll
        for (int c = 0; c < 8; ++c)
#pragma unroll
            for (int rg = 0; rg < 4; ++rg)
                Lf[(w * 32 + m * 16 + lgrp * 4 + rg) * DIM + c * 16 + lrow] = acc[m][c][rg];
    __syncthreads();

    const float4* Lf4 = (const float4*)smem;
    for (int idx = t; idx < 4096; idx += 256) {
        const int row = idx >> 5, s = idx & 31;
        const int gr = rbase + row;
        if (gr < N_NODES) {
            float4 v = Lf4[idx];
            uint2 o;
            o.x = pk_bf16(v.x, v.y);
            o.y = pk_bf16(v.z, v.w);
            O[(size_t)gr * 32 + s] = o;
        }
    }
}

// ---------------- Pass B body: counting sort; offsets from chist -----------

__device__ void sort_scatter_body(const int* __restrict__ src,
                                  const int* __restrict__ dst,
                                  const int* __restrict__ chist,
                                  unsigned* __restrict__ sorted,
                                  int* __restrict__ bbase_g,
                                  int bid, char* smem) {
    int* hist  = (int*)smem;
    int* sc    = hist + 256;
    int* lbase = sc + 256;
    int* lcur  = lbase + 256;
    int* gbase = lcur + 256;
    unsigned* sl = (unsigned*)(smem + 5 * 1024);   // CHUNK entries

    const int t = threadIdx.x;
    const int eb = bid * CHUNK;
    const int cnt = min(CHUNK, N_EDGES - eb);

    int sum = 0, myoff = 0;
    for (int c = 0; c < GRID; ++c) {
        int v = chist[c * 256 + t];
        if (c == bid) myoff = sum;
        sum += v;
    }
    hist[t] = chist[bid * 256 + t];
    sc[t] = sum;
    __syncthreads();
    for (int off = 1; off < 256; off <<= 1) {
        int u = (t >= off) ? sc[t - off] : 0;
        __syncthreads();
        sc[t] += u;
        __syncthreads();
    }
    gbase[t] = (sc[t] - sum) + myoff;
    if (bid == 0) bbase_g[t] = sc[t] - sum;   // exclusive scan of bucket totals
    __syncthreads();

    sc[t] = hist[t];
    __syncthreads();
    for (int off = 1; off < 256; off <<= 1) {
        int u = (t >= off) ? sc[t - off] : 0;
        __syncthreads();
        sc[t] += u;
        __syncthreads();
    }
    int ex = sc[t] - hist[t];
    lbase[t] = ex;
    lcur[t] = ex;
    __syncthreads();

    for (int i = t; i < cnt; i += 256) {
        int s = src[eb + i], d = dst[eb + i];
        int b = d >> 8;
        int p = atomicAdd(&lcur[b], 1);
        sl[p] = ((unsigned)b << 24) | ((unsigned)(d & 255) << 16) | (unsigned)s;
    }
    __syncthreads();
    for (int i = t; i < cnt; i += 256) {
        unsigned rec = sl[i];
        int b = rec >> 24;
        sorted[gbase[b] + (i - lbase[b])] = rec;
    }
}

// ---------------- Fused dispatch: sort blocks first, ALL gemm1 backfills ---

__global__ __launch_bounds__(256, 2) void sort_gemm(const int* __restrict__ src,
                                                    const int* __restrict__ dst,
                                                    const int* __restrict__ chist,
                                                    unsigned* __restrict__ sorted,
                                                    int* __restrict__ bbase_g,
                                                    const float* __restrict__ X,
                                                    const uint4* __restrict__ fWh,
                                                    const uint4* __restrict__ fWl,
                                                    uint2* __restrict__ O) {
    __shared__ __align__(16) char smem[65536];
    if (blockIdx.x < GRID)
        sort_scatter_body(src, dst, chist, sorted, bbase_g, blockIdx.x, smem);
    else
        gemm_body(X, fWh, fWl, O, blockIdx.x - GRID, smem);
}

// ---------------- Pass C: per-bucket CSR finalize (standalone, 5/CU) -------

__global__ __launch_bounds__(256) void csr_build(const unsigned* __restrict__ sorted,
                                                 const int* __restrict__ bbase,
                                                 int* __restrict__ rowptr,
                                                 float* __restrict__ dinv,
                                                 int* __restrict__ csr) {
    __shared__ __align__(16) char smem[3 * 1024 + SEG_CAP * 4];   // 27.6 KB
    int* hist = (int*)smem;
    int* sc   = hist + 256;
    int* lcur = sc + 256;
    int* seg  = (int*)(smem + 3 * 1024);

    const int k = blockIdx.x;
    const int t = threadIdx.x;
    const int base = bbase[k];
    const int cntk = ((k == 255) ? N_EDGES : bbase[k + 1]) - base;
    if (k == 0 && t == 0) rowptr[N_NODES] = N_EDGES;

    hist[t] = 0;
    __syncthreads();
    for (int i = t; i < cntk; i += 256)
        atomicAdd(&hist[(sorted[base + i] >> 16) & 255], 1);
    __syncthreads();

    const int node = (k << 8) + t;
    const int dv = hist[t];
    if (node < N_NODES) dinv[node] = rsqrtf((float)dv + 1.0f);   // +1 self-loop

    sc[t] = dv;
    __syncthreads();
    for (int off = 1; off < 256; off <<= 1) {
        int u = (t >= off) ? sc[t - off] : 0;
        __syncthreads();
        sc[t] += u;
        __syncthreads();
    }
    int ex = sc[t] - dv;
    if (node < N_NODES) rowptr[node] = base + ex;
    lcur[t] = ex;
    __syncthreads();

    if (cntk <= SEG_CAP) {
        for (int i = t; i < cntk; i += 256) {
            unsigned rec = sorted[base + i];
            int p = atomicAdd(&lcur[(rec >> 16) & 255], 1);
            seg[p] = (int)(rec & 0xFFFFu);
        }
        __syncthreads();
        for (int i = t; i < cntk; i += 256)
            csr[base + i] = seg[i];
    } else {
        for (int i = t; i < cntk; i += 256) {
            unsigned rec = sorted[base + i];
            int p = atomicAdd(&lcur[(rec >> 16) & 255], 1);
            csr[base + p] = (int)(rec & 0xFFFFu);
        }
    }
}

// ---------------- quarter-wave aggregation (uint4 = 16B/lane gathers) ------
// MLP-deepened: 4 rows in flight per quarter (j+=16). Per-lane addition
// order identical to two j+=8 iterations -> bit-identical results.

#define ACC8_D(v, d) do { \
        a0 = fmaf((d), bf_lo((v).x), a0); a1 = fmaf((d), bf_hi((v).x), a1); \
        a2 = fmaf((d), bf_lo((v).y), a2); a3 = fmaf((d), bf_hi((v).y), a3); \
        a4 = fmaf((d), bf_lo((v).z), a4); a5 = fmaf((d), bf_hi((v).z), a5); \
        a6 = fmaf((d), bf_lo((v).w), a6); a7 = fmaf((d), bf_hi((v).w), a7); } while (0)

#define ACC8_P(v) do { \
        a0 += bf_lo((v).x); a1 += bf_hi((v).x); \
        a2 += bf_lo((v).y); a3 += bf_hi((v).y); \
        a4 += bf_lo((v).z); a5 += bf_hi((v).z); \
        a6 += bf_lo((v).w); a7 += bf_hi((v).w); } while (0)

// ---------------- layer-1 aggregate: per-edge dinv fmaf; writes h1' hi/lo --
// h1' = dinv[n] * relu(agg*dn + b1)  -> pre-scaled for layer 2 (linearity).

__global__ __launch_bounds__(256) void aggregate_h1(const uint2* __restrict__ H2,
                                                    const int* __restrict__ rowptr,
                                                    const int* __restrict__ csr,
                                                    const float* __restrict__ dinv,
                                                    const float4* __restrict__ b4,
                                                    uint4* __restrict__ h1h4,
                                                    uint4* __restrict__ h1l4) {
    const int node = blockIdx.x * 4 + (threadIdx.x >> 6);
    if (node >= N_NODES) return;
    const int lane = threadIdx.x & 63;
    const int q = lane >> 4, l16 = lane & 15;
    const uint4* H4 = (const uint4*)H2;

    const float dn = dinv[node];
    float a0 = 0.f, a1 = 0.f, a2 = 0.f, a3 = 0.f,
          a4 = 0.f, a5 = 0.f, a6 = 0.f, a7 = 0.f;
    if (q == 0) {                          // self-loop term: weight dinv[node]
        uint4 v = H4[(size_t)node * 16 + l16];
        ACC8_D(v, dn);
    }

    int j = rowptr[node];
    const int end = rowptr[node + 1];
    for (; j + 16 <= end; j += 16) {       // 4 rows in flight per quarter
        int s0 = csr[j + q],      s1 = csr[j + 4 + q];
        int s2 = csr[j + 8 + q],  s3 = csr[j + 12 + q];
        uint4 v0 = H4[(size_t)s0 * 16 + l16]; float d0 = dinv[s0];
        uint4 v1 = H4[(size_t)s1 * 16 + l16]; float d1 = dinv[s1];
        uint4 v2 = H4[(size_t)s2 * 16 + l16]; float d2 = dinv[s2];
        uint4 v3 = H4[(size_t)s3 * 16 + l16]; float d3 = dinv[s3];
        ACC8_D(v0, d0); ACC8_D(v1, d1); ACC8_D(v2, d2); ACC8_D(v3, d3);
    }
    if (j + 8 <= end) {
        int s0 = csr[j + q], s1 = csr[j + 4 + q];
        uint4 v0 = H4[(size_t)s0 * 16 + l16]; float d0 = dinv[s0];
        uint4 v1 = H4[(size_t)s1 * 16 + l16]; float d1 = dinv[s1];
        ACC8_D(v0, d0); ACC8_D(v1, d1);
        j += 8;
    }
    if (j + 4 <= end) {
        int s = csr[j + q];
        uint4 v = H4[(size_t)s * 16 + l16]; float d = dinv[s];
        ACC8_D(v, d);
        j += 4;
    }
    if (q < end - j) {
        int s = csr[j + q];
        uint4 v = H4[(size_t)s * 16 + l16]; float d = dinv[s];
        ACC8_D(v, d);
    }

    a0 += __shfl_xor(a0, 16, 64); a1 += __shfl_xor(a1, 16, 64);
    a2 += __shfl_xor(a2, 16, 64); a3 += __shfl_xor(a3, 16, 64);
    a4 += __shfl_xor(a4, 16, 64); a5 += __shfl_xor(a5, 16, 64);
    a6 += __shfl_xor(a6, 16, 64); a7 += __shfl_xor(a7, 16, 64);
    a0 += __shfl_xor(a0, 32, 64); a1 += __shfl_xor(a1, 32, 64);
    a2 += __shfl_xor(a2, 32, 64); a3 += __shfl_xor(a3, 32, 64);
    a4 += __shfl_xor(a4, 32, 64); a5 += __shfl_xor(a5, 32, 64);
    a6 += __shfl_xor(a6, 32, 64); a7 += __shfl_xor(a7, 32, 64);

    if (lane < 16) {
        float4 bbA = b4[l16 * 2], bbB = b4[l16 * 2 + 1];
        float o0 = fmaxf(a0 * dn + bbA.x, 0.f), o1 = fmaxf(a1 * dn + bbA.y, 0.f);
        float o2 = fmaxf(a2 * dn + bbA.z, 0.f), o3 = fmaxf(a3 * dn + bbA.w, 0.f);
        float o4 = fmaxf(a4 * dn + bbB.x, 0.f), o5 = fmaxf(a5 * dn + bbB.y, 0.f);
        float o6 = fmaxf(a6 * dn + bbB.z, 0.f), o7 = fmaxf(a7 * dn + bbB.w, 0.f);
        o0 *= dn; o1 *= dn; o2 *= dn; o3 *= dn;
        o4 *= dn; o5 *= dn; o6 *= dn; o7 *= dn;
        unsigned h0 = rne_bf16(o0), h1 = rne_bf16(o1), h2 = rne_bf16(o2), h3 = rne_bf16(o3);
        unsigned h4 = rne_bf16(o4), h5 = rne_bf16(o5), h6 = rne_bf16(o6), h7 = rne_bf16(o7);
        uint4 hv;
        hv.x = h0 | (h1 << 16); hv.y = h2 | (h3 << 16);
        hv.z = h4 | (h5 << 16); hv.w = h6 | (h7 << 16);
        uint4 lv;
        lv.x = rne_bf16(o0 - __uint_as_float(h0 << 16)) |
               (rne_bf16(o1 - __uint_as_float(h1 << 16)) << 16);
        lv.y = rne_bf16(o2 - __uint_as_float(h2 << 16)) |
               (rne_bf16(o3 - __uint_as_float(h3 << 16)) << 16);
        lv.z = rne_bf16(o4 - __uint_as_float(h4 << 16)) |
               (rne_bf16(o5 - __uint_as_float(h5 << 16)) << 16);
        lv.w = rne_bf16(o6 - __uint_as_float(h6 << 16)) |
               (rne_bf16(o7 - __uint_as_float(h7 << 16)) << 16);
        h1h4[(size_t)node * 16 + l16] = hv;
        h1l4[(size_t)node * 16 + l16] = lv;
    }
}

// ---------------- final aggregate: hp2 pre-scaled -> plain adds ------------

__global__ __launch_bounds__(256) void aggregate_out(const uint2* __restrict__ H2,
                                                     const int* __restrict__ rowptr,
                                                     const int* __restrict__ csr,
                                                     const float* __restrict__ dinv,
                                                     const float4* __restrict__ b4,
                                                     float4* __restrict__ out) {
    const int node = blockIdx.x * 4 + (threadIdx.x >> 6);
    if (node >= N_NODES) return;
    const int lane = threadIdx.x & 63;
    const int q = lane >> 4, l16 = lane & 15;
    const uint4* H4 = (const uint4*)H2;

    float a0 = 0.f, a1 = 0.f, a2 = 0.f, a3 = 0.f,
          a4 = 0.f, a5 = 0.f, a6 = 0.f, a7 = 0.f;
    if (q == 0) {                          // self-loop term (pre-scaled row)
        uint4 v = H4[(size_t)node * 16 + l16];
        ACC8_P(v);
    }

    int j = rowptr[node];
    const int end = rowptr[node + 1];
    for (; j + 16 <= end; j += 16) {       // 4 rows in flight per quarter
        int s0 = csr[j + q],      s1 = csr[j + 4 + q];
        int s2 = csr[j + 8 + q],  s3 = csr[j + 12 + q];
        uint4 v0 = H4[(size_t)s0 * 16 + l16];
        uint4 v1 = H4[(size_t)s1 * 16 + l16];
        uint4 v2 = H4[(size_t)s2 * 16 + l16];
        uint4 v3 = H4[(size_t)s3 * 16 + l16];
        ACC8_P(v0); ACC8_P(v1); ACC8_P(v2); ACC8_P(v3);
    }
    if (j + 8 <= end) {
        int s0 = csr[j + q], s1 = csr[j + 4 + q];
        uint4 v0 = H4[(size_t)s0 * 16 + l16];
        uint4 v1 = H4[(size_t)s1 * 16 + l16];
        ACC8_P(v0); ACC8_P(v1);
        j += 8;
    }
    if (j + 4 <= end) {
        int s = csr[j + q];
        uint4 v = H4[(size_t)s * 16 + l16];
        ACC8_P(v);
        j += 4;
    }
    if (q < end - j) {
        int s = csr[j + q];
        uint4 v = H4[(size_t)s * 16 + l16];
        ACC8_P(v);
    }

    a0 += __shfl_xor(a0, 16, 64); a1 += __shfl_xor(a1, 16, 64);
    a2 += __shfl_xor(a2, 16, 64); a3 += __shfl_xor(a3, 16, 64);
    a4 += __shfl_xor(a4, 16, 64); a5 += __shfl_xor(a5, 16, 64);
    a6 += __shfl_xor(a6, 16, 64); a7 += __shfl_xor(a7, 16, 64);
    a0 += __shfl_xor(a0, 32, 64); a1 += __shfl_xor(a1, 32, 64);
    a2 += __shfl_xor(a2, 32, 64); a3 += __shfl_xor(a3, 32, 64);
    a4 += __shfl_xor(a4, 32, 64); a5 += __shfl_xor(a5, 32, 64);
    a6 += __shfl_xor(a6, 32, 64); a7 += __shfl_xor(a7, 32, 64);

    if (lane < 16) {
        const float dn = dinv[node];
        float4 bbA = b4[l16 * 2], bbB = b4[l16 * 2 + 1];
        float4 oA, oB;
        oA.x = a0 * dn + bbA.x; oA.y = a1 * dn + bbA.y;
        oA.z = a2 * dn + bbA.z; oA.w = a3 * dn + bbA.w;
        oB.x = a4 * dn + bbB.x; oB.y = a5 * dn + bbB.y;
        oB.z = a6 * dn + bbB.z; oB.w = a7 * dn + bbB.w;
        out[(size_t)node * 32 + l16 * 2]     = oA;
        out[(size_t)node * 32 + l16 * 2 + 1] = oB;
    }
}

// ---------------- layer-2 GEMM: A pre-split bf16 hi/lo, staged B -----------

__global__ __launch_bounds__(256, 2) void gemm_xw2(const uint2* __restrict__ h1h,
                                                   const uint2* __restrict__ h1l,
                                                   const uint4* __restrict__ fWh,
                                                   const uint4* __restrict__ fWl,
                                                   uint2* __restrict__ O) {
    __shared__ __align__(16) char smem[65536];
    const int t = threadIdx.x;

    {   // stage W fragments: hi at [0,32KB), lo at [32KB,64KB)
        uint4* s4 = (uint4*)smem;
        for (int i = t; i < 2048; i += 256) {
            s4[i] = fWh[i];
            s4[2048 + i] = fWl[i];
        }
    }
    __syncthreads();

    const int w = t >> 6, lane = t & 63;
    const int lrow = lane & 15, lgrp = lane >> 4;
    const int rbase = blockIdx.x * 128;

    bf16x8 Ah[2][4], Al[2][4];
    const bf16x8 zz = (bf16x8){0,0,0,0,0,0,0,0};
#pragma unroll
    for (int m = 0; m < 2; ++m) {
        const int r = rbase + w * 32 + m * 16 + lrow;
        const bool ok = (r < N_NODES);
        const uint2* ph = h1h + (size_t)r * 32 + lgrp * 2;
        const uint2* pl = h1l + (size_t)r * 32 + lgrp * 2;
#pragma unroll
        for (int q = 0; q < 4; ++q) {
            Ah[m][q] = ok ? *(const bf16x8*)(ph + q * 8) : zz;
            Al[m][q] = ok ? *(const bf16x8*)(pl + q * 8) : zz;
        }
    }

    f32x4 acc[2][8];
#pragma unroll
    for (int m = 0; m < 2; ++m)
#pragma unroll
        for (int c = 0; c < 8; ++c)
            acc[m][c] = (f32x4){0.f, 0.f, 0.f, 0.f};

    const bf16x8* Bh = (const bf16x8*)smem;
    const bf16x8* Bl = (const bf16x8*)(smem + 32768);
#pragma unroll
    for (int c = 0; c < 8; ++c) {
#pragma unroll
        for (int q = 0; q < 4; ++q) {
            bf16x8 bh = Bh[(c * 4 + q) * 64 + lane];
            bf16x8 bl = Bl[(c * 4 + q) * 64 + lane];
#pragma unroll
            for (int m = 0; m < 2; ++m) {
                acc[m][c] = __builtin_amdgcn_mfma_f32_16x16x32_bf16(Ah[m][q], bh, acc[m][c], 0, 0, 0);
                acc[m][c] = __builtin_amdgcn_mfma_f32_16x16x32_bf16(Al[m][q], bh, acc[m][c], 0, 0, 0);
                acc[m][c] = __builtin_amdgcn_mfma_f32_16x16x32_bf16(Ah[m][q], bl, acc[m][c], 0, 0, 0);
            }
        }
    }

    __syncthreads();
    float* Lf = (float*)smem;
#pragma unroll
    for (int m = 0; m < 2; ++m)
#pragma unroll
        for (int c = 0; c < 8; ++c)
#pragma unroll
            for (int rg = 0; rg < 4; ++rg)
                Lf[(w * 32 + m * 16 + lgrp * 4 + rg) * DIM + c * 16 + lrow] = acc[m][c][rg];
    __syncthreads();

    const float4* Lf4 = (const float4*)smem;
    for (int idx = t; idx < 4096; idx += 256) {
        const int row = idx >> 5, s = idx & 31;
        const int gr = rbase + row;
        if (gr < N_NODES) {
            float4 v = Lf4[idx];
            uint2 o;
            o.x = pk_bf16(v.x, v.y);
            o.y = pk_bf16(v.z, v.w);
            O[(size_t)gr * 32 + s] = o;
        }
    }
}

// ---------------- launch ----------------

extern "C" void kernel_launch(void* const* d_in, const int* in_sizes, int n_in,
                              void* d_out, int out_size, void* d_ws, size_t ws_size,
                              hipStream_t stream) {
    const float* x  = (const float*)d_in[0];
    const int*   ei = (const int*)d_in[1];
    const float* W1 = (const float*)d_in[2];
    const float* b1 = (const float*)d_in[3];
    const float* W2 = (const float*)d_in[4];
    const float* b2 = (const float*)d_in[5];
    float* out = (float*)d_out;

    const int* src = ei;             // edge_index[0]
    const int* dst = ei + N_EDGES;   // edge_index[1]

    char* p = (char*)d_ws;
    int*      chist  = (int*)p;              p += GRID * 256 * 4;              // 200 KB
    float*    dinv   = (float*)p;            p += ((N_NODES * 4 + 1023) & ~1023);
    int*      rowptr = (int*)p;              p += (((N_NODES + 1) * 4 + 1023) & ~1023);
    unsigned* sorted = (unsigned*)p;         p += ((N_EDGES * 4 + 1023) & ~1023);
    int*      csr    = (int*)p;              p += ((N_EDGES * 4 + 1023) & ~1023);
    int*      bbase  = (int*)p;              p += 1024;                        // 256 ints
    uint4*    f1h    = (uint4*)p;            p += 32768;                       // W1 hi frags
    uint4*    f1l    = (uint4*)p;            p += 32768;                       // W1 lo frags
    uint4*    f2h    = (uint4*)p;            p += 32768;                       // W2 hi frags
    uint4*    f2l    = (uint4*)p;            p += 32768;                       // W2 lo frags
    uint2*    hp     = (uint2*)p;            p += (size_t)N_NODES * DIM * 2;   // bf16 layer1 lin table
    uint2*    h1h    = (uint2*)p;            p += (size_t)N_NODES * DIM * 2;   // h1' hi bf16 (pre-scaled)
    uint2*    h1l    = (uint2*)p;            p += (size_t)N_NODES * DIM * 2;   // h1' lo bf16
    uint2*    hp2    = (uint2*)p;                                              // bf16 layer2 lin (pre-scaled)

    const int aggBlocks = (N_NODES + 3) / 4;     // 12500

    // ---- pass A + W-fragment build (co-gridded) ----
    chunk_hist_fragw<<<GRID + 16, 256, 0, stream>>>(dst, chist, W1, W2,
                                                    f1h, f1l, f2h, f2l);
    // ---- sort + ALL layer-1 gemm co-gridded (587 blocks; staged-B gemm) ----
    sort_gemm<<<GRID + GA, 256, 0, stream>>>(src, dst, chist, sorted, bbase,
                                             x, f1h, f1l, hp);
    // ---- CSR finalize (196 blocks, 27.6 KB LDS -> 5/CU, all co-resident) ----
    csr_build<<<GRID, 256, 0, stream>>>(sorted, bbase, rowptr, dinv, csr);

    // ---- layer 1 aggregate (+b1, relu, pre-scale) -> h1' hi/lo ----
    aggregate_h1<<<aggBlocks, 256, 0, stream>>>(hp, rowptr, csr, dinv,
                                                (const float4*)b1,
                                                (uint4*)h1h, (uint4*)h1l);

    // ---- layer 2 MFMA GEMM (pre-split A, staged B) -> hp2 ----
    gemm_xw2<<<GEMM_BLOCKS, 256, 0, stream>>>(h1h, h1l, f2h, f2l, hp2);

    // ---- final aggregate (plain adds) -> out ----
    aggregate_out<<<aggBlocks, 256, 0, stream>>>(hp2, rowptr, csr, dinv,
                                                 (const float4*)b2, (float4*)out);
}